// Round 5
// baseline (406.687 us; speedup 1.0000x reference)
//
#include <hip/hip_runtime.h>

// BiLSTM for MI355X (gfx950) — round 5: two-kernel split.
//  K1 gpre_gemm: gpre[B*T][64] = relu(x@W0+b0)@Wfx + bf' (split-bf16 MFMA, R4-verified
//     numerics), fp32 into d_ws. Weights loaded per block, used once -> no persistent
//     per-lane arrays -> no AGPR shuttling.
//  K2 lstm_scan: one wave per sequence; per step: 1 gpre load (prefetch depth 8)
//     + 16 DPP row_ror h-fmacs + gate math (R2..R4-verified). Epilogue recomputes
//     xh[255] exactly from x, then bwd single-step + head MLP (R4-verified).
//  Fallback: if ws_size < 268 MB, launch the unchanged R4 fused kernel.

typedef __attribute__((ext_vector_type(8))) short short8;
typedef __attribute__((ext_vector_type(4))) float floatx4;

union F8 { uint32_t u[4]; short8 v; };

#define LDW 66  // LDS row stride (dwords): 66 mod 32 = 2 -> <=2-way bank aliasing (free)

__device__ __forceinline__ float tanh_fast(float x) {
    float e = __expf(-2.f * x);
    return __fdividef(2.f, 1.f + e) - 1.f;
}

// rotate v right by S within each row of 16 lanes (DPP row_ror:S)
#define ROT(v, S) __int_as_float(__builtin_amdgcn_mov_dpp(__float_as_int(v), 0x120 | (S), 0xf, 0xf, false))

// split f[0..7] (fp32) into truncated-bf16 hi and residual-bf16 lo fragments
__device__ __forceinline__ void split_pack(const float* f, uint32_t* hi, uint32_t* lo) {
#pragma unroll
    for (int i = 0; i < 4; ++i) {
        uint32_t u0 = __float_as_uint(f[2 * i]), u1 = __float_as_uint(f[2 * i + 1]);
        hi[i] = (u0 >> 16) | (u1 & 0xFFFF0000u);
        float r0 = f[2 * i]     - __uint_as_float(u0 & 0xFFFF0000u);
        float r1 = f[2 * i + 1] - __uint_as_float(u1 & 0xFFFF0000u);
        uint32_t v0 = __float_as_uint(r0), v1 = __float_as_uint(r1);
        lo[i] = (v0 >> 16) | (v1 & 0xFFFF0000u);
    }
}

// ===================== K1: gpre GEMM =====================
// grid 16384 x 256 threads; block handles 64 rows of M=1048576; wave w rows 16w..16w+15.
__global__ __launch_bounds__(256, 2)
void gpre_gemm(const float* __restrict__ x,
               const float* __restrict__ W0, const float* __restrict__ b0,
               const float* __restrict__ Wf, const float* __restrict__ bf,
               float* __restrict__ gpre)
{
    __shared__ __align__(16) float xtile[64 * 20];          // block x rows
    __shared__ __align__(16) float xh_t[4][16 * LDW];       // per-wave transpose buf

    const int tid  = threadIdx.x;
    const int wv   = tid >> 6;
    const int j    = tid & 63;
    const int nl   = j & 15;
    const int quad = j >> 4;
    const int r0   = blockIdx.x * 64;

    // ---- stage x[64][20] into LDS (320 float4, coalesced)
    {
        const float4* src = (const float4*)(x + (size_t)r0 * 20);
        float4* dst = (float4*)xtile;
        if (tid < 256)       dst[tid]       = src[tid];
        if (tid < 64)        dst[tid + 256] = src[tid + 256];
    }
    __syncthreads();

    // ---- B fragments (loaded per block, used once)
    F8 B1h[4], B1l[4];
#pragma unroll
    for (int T = 0; T < 4; ++T) {
        float w[8];
#pragma unroll
        for (int e = 0; e < 8; ++e) {
            int k = quad * 8 + e;
            w[e] = (k < 20) ? W0[k * 64 + T * 16 + nl] : 0.f;
        }
        split_pack(w, B1h[T].u, B1l[T].u);
    }
    F8 B2h[4][2], B2l[4][2];
#pragma unroll
    for (int T = 0; T < 4; ++T)
#pragma unroll
        for (int KH = 0; KH < 2; ++KH) {
            float w[8];
#pragma unroll
            for (int e = 0; e < 8; ++e) {
                int k = KH * 32 + quad * 8 + e;
                w[e] = Wf[k * 64 + T * 16 + nl];
            }
            split_pack(w, B2h[T][KH].u, B2l[T][KH].u);
        }

    // ---- stage 1: xh = relu(x@W0+b0) for this wave's 16 rows
    float xk[8];
#pragma unroll
    for (int e = 0; e < 8; ++e) {
        int k = quad * 8 + e;
        xk[e] = (k < 20) ? xtile[(wv * 16 + nl) * 20 + k] : 0.f;
    }
    F8 A1h, A1l;
    split_pack(xk, A1h.u, A1l.u);

    floatx4 acc1[4];
#pragma unroll
    for (int T = 0; T < 4; ++T) {
        float bv = b0[T * 16 + nl];
        acc1[T] = (floatx4){bv, bv, bv, bv};
    }
#pragma unroll
    for (int T = 0; T < 4; ++T) {
        acc1[T] = __builtin_amdgcn_mfma_f32_16x16x32_bf16(A1h.v, B1h[T].v, acc1[T], 0, 0, 0);
        acc1[T] = __builtin_amdgcn_mfma_f32_16x16x32_bf16(A1l.v, B1h[T].v, acc1[T], 0, 0, 0);
        acc1[T] = __builtin_amdgcn_mfma_f32_16x16x32_bf16(A1h.v, B1l[T].v, acc1[T], 0, 0, 0);
    }

    // relu + transpose via wave-private LDS
#pragma unroll
    for (int T = 0; T < 4; ++T)
#pragma unroll
        for (int reg = 0; reg < 4; ++reg)
            xh_t[wv][(quad * 4 + reg) * LDW + T * 16 + nl] = fmaxf(acc1[T][reg], 0.f);
    __builtin_amdgcn_wave_barrier();

    // ---- stage 2: gpre = xh@Wfx + bf'  (f-gate +1 folded into bias col 32..47)
    F8 A2h[2], A2l[2];
#pragma unroll
    for (int KH = 0; KH < 2; ++KH) {
        float xe[8];
#pragma unroll
        for (int e = 0; e < 8; ++e)
            xe[e] = xh_t[wv][nl * LDW + KH * 32 + quad * 8 + e];
        split_pack(xe, A2h[KH].u, A2l[KH].u);
    }

    floatx4 acc2[4];
#pragma unroll
    for (int T = 0; T < 4; ++T) {
        float bv = bf[T * 16 + nl] + ((T == 2) ? 1.f : 0.f);
        acc2[T] = (floatx4){bv, bv, bv, bv};
    }
#pragma unroll
    for (int T = 0; T < 4; ++T)
#pragma unroll
        for (int KH = 0; KH < 2; ++KH) {
            acc2[T] = __builtin_amdgcn_mfma_f32_16x16x32_bf16(A2h[KH].v, B2h[T][KH].v, acc2[T], 0, 0, 0);
            acc2[T] = __builtin_amdgcn_mfma_f32_16x16x32_bf16(A2l[KH].v, B2h[T][KH].v, acc2[T], 0, 0, 0);
            acc2[T] = __builtin_amdgcn_mfma_f32_16x16x32_bf16(A2h[KH].v, B2l[T][KH].v, acc2[T], 0, 0, 0);
        }

    // ---- store gpre rows r0+16w+quad*4+reg, cols T*16+nl
    float* gp = gpre + (size_t)(r0 + wv * 16) * 64;
#pragma unroll
    for (int T = 0; T < 4; ++T)
#pragma unroll
        for (int reg = 0; reg < 4; ++reg)
            gp[(quad * 4 + reg) * 64 + T * 16 + nl] = acc2[T][reg];
}

// ===================== K2: serial scan + epilogue =====================
// grid 1024 x 256 threads; wave w handles sequence b = blockIdx*4+w.
__global__ __launch_bounds__(256, 4)
void lstm_scan(const float* __restrict__ gpre,
               const float* __restrict__ x,
               const float* __restrict__ W0, const float* __restrict__ b0,
               const float* __restrict__ Wf,
               const float* __restrict__ Wb, const float* __restrict__ bb,
               const float* __restrict__ W1, const float* __restrict__ b1,
               const float* __restrict__ W2, const float* __restrict__ b2,
               const float* __restrict__ W3, const float* __restrict__ b3,
               float* __restrict__ out)
{
    __shared__ __align__(16) float xh_sh[4][64];
    __shared__ __align__(16) float h_sh[4][48];   // [0:16) hf, [16:32) hb, [32:48) l2

    const int wv   = threadIdx.x >> 6;
    const int j    = threadIdx.x & 63;
    const int b    = blockIdx.x * 4 + wv;
    const int nl   = j & 15;
    const int quad = j >> 4;

    // runtime probe of row_ror source direction (R2..R4-verified)
    int rot1 = __builtin_amdgcn_mov_dpp(j, 0x121, 0xf, 0xf, false);
    const bool plus = ((rot1 & 15) == ((nl + 1) & 15));

    float wfhp[16];
#pragma unroll
    for (int s = 0; s < 16; ++s) {
        const int srcq = plus ? ((nl + s) & 15) : ((nl + 16 - s) & 15);
        wfhp[s] = Wf[(64 + srcq) * 64 + j];
    }

    const float gmul  = (quad == 1) ? -2.f : -1.f;   // f-gate +1 already folded in gpre
    const float amul  = (quad == 1) ? 2.f : 1.f;
    const float aadd  = (quad == 1) ? -1.f : 0.f;
    const bool  b0sel = (quad & 1) != 0;
    const bool  b1sel = (quad & 2) != 0;

    float c = 0.f, hh = 0.f;
    const float* gb = gpre + (size_t)b * (256 * 64);

    // prefetch depth 8
    float gbuf[8];
#pragma unroll
    for (int i = 0; i < 8; ++i) gbuf[i] = gb[i * 64 + j];

#pragma unroll 1
    for (int t = 0; t < 256; t += 8) {
#pragma unroll
        for (int i = 0; i < 8; ++i) {
            float gated0 = gbuf[i];
            {
                int tf = t + 8 + i; tf = (tf > 255) ? 255 : tf;
                gbuf[i] = gb[tf * 64 + j];
            }
            // h @ Wfh[:,j] : 16 DPP fmacs, 4 chains
            float v0 = hh * wfhp[0];
            float v1 = ROT(hh, 1) * wfhp[1];
            float v2 = ROT(hh, 2) * wfhp[2];
            float v3 = ROT(hh, 3) * wfhp[3];
            v0 = fmaf(ROT(hh, 4),  wfhp[4],  v0);
            v1 = fmaf(ROT(hh, 5),  wfhp[5],  v1);
            v2 = fmaf(ROT(hh, 6),  wfhp[6],  v2);
            v3 = fmaf(ROT(hh, 7),  wfhp[7],  v3);
            v0 = fmaf(ROT(hh, 8),  wfhp[8],  v0);
            v1 = fmaf(ROT(hh, 9),  wfhp[9],  v1);
            v2 = fmaf(ROT(hh, 10), wfhp[10], v2);
            v3 = fmaf(ROT(hh, 11), wfhp[11], v3);
            v0 = fmaf(ROT(hh, 12), wfhp[12], v0);
            v1 = fmaf(ROT(hh, 13), wfhp[13], v1);
            v2 = fmaf(ROT(hh, 14), wfhp[14], v2);
            v3 = fmaf(ROT(hh, 15), wfhp[15], v3);
            float gated = gated0 + ((v0 + v1) + (v2 + v3));

            float e = __expf(gmul * gated);
            float y = __fdividef(1.f, 1.f + e);
            float a = fmaf(y, amul, aadd);

            float d1 = __shfl_xor(a, 16);
            float d2 = __shfl_xor(a, 32);
            float d3 = __shfl_xor(a, 48);
            float lo  = b0sel ? d1 : a;
            float hi  = b0sel ? d3 : d2;
            float lo1 = b0sel ? a  : d1;
            float hi1 = b0sel ? d2 : d3;
            float ai = b1sel ? hi  : lo;
            float ag = b1sel ? hi1 : lo1;
            float af = b1sel ? lo  : hi;
            float ao = b1sel ? lo1 : hi1;

            c  = fmaf(af, c, ai * ag);
            hh = ao * tanh_fast(c);
        }
    }

    // ---- epilogue: recompute xh[255] exactly from x (fp32)
    {
        const float* xr = x + (size_t)b * (256 * 20) + 255 * 20;
        float s = b0[j];
#pragma unroll
        for (int k = 0; k < 20; ++k) s = fmaf(xr[k], W0[k * 64 + j], s);
        xh_sh[wv][j] = fmaxf(s, 0.f);
        if (j < 16) h_sh[wv][j] = hh;
    }
    __builtin_amdgcn_wave_barrier();

    // backward LSTM output at t=T-1: one step from zero state on xh[255]
    {
        float u0 = bb[j], u1 = 0.f, u2 = 0.f, u3 = 0.f;
        const float* xr = xh_sh[wv];
#pragma unroll
        for (int k4 = 0; k4 < 16; ++k4) {
            u0 = fmaf(xr[4 * k4 + 0], Wb[(4 * k4 + 0) * 64 + j], u0);
            u1 = fmaf(xr[4 * k4 + 1], Wb[(4 * k4 + 1) * 64 + j], u1);
            u2 = fmaf(xr[4 * k4 + 2], Wb[(4 * k4 + 2) * 64 + j], u2);
            u3 = fmaf(xr[4 * k4 + 3], Wb[(4 * k4 + 3) * 64 + j], u3);
        }
        float gated = (u0 + u1) + (u2 + u3);
        float e = __expf(gmul * gated);   // f-gate irrelevant (c_prev=0)
        float y = __fdividef(1.f, 1.f + e);
        float a = fmaf(y, amul, aadd);
        float ai = __shfl(a, nl, 64);
        float ag = __shfl(a, nl + 16, 64);
        float ao = __shfl(a, nl + 48, 64);
        float cb = ai * ag;
        float hb = ao * tanh_fast(cb);
        __builtin_amdgcn_wave_barrier();
        if (j < 16) h_sh[wv][16 + j] = hb;
        __builtin_amdgcn_wave_barrier();
    }

    // head MLP
    {
        float u0 = b1[j], u1 = 0.f, u2 = 0.f, u3 = 0.f;
        const float4* hs = (const float4*)h_sh[wv];
#pragma unroll
        for (int k4 = 0; k4 < 8; ++k4) {
            float4 v = hs[k4];
            u0 = fmaf(v.x, W1[(4 * k4 + 0) * 64 + j], u0);
            u1 = fmaf(v.y, W1[(4 * k4 + 1) * 64 + j], u1);
            u2 = fmaf(v.z, W1[(4 * k4 + 2) * 64 + j], u2);
            u3 = fmaf(v.w, W1[(4 * k4 + 3) * 64 + j], u3);
        }
        float l1 = fmaxf((u0 + u1) + (u2 + u3), 0.f);
        __builtin_amdgcn_wave_barrier();
        xh_sh[wv][j] = l1;
        __builtin_amdgcn_wave_barrier();

        if (j < 16) {
            float v0 = b2[j], v1 = 0.f, v2 = 0.f, v3 = 0.f;
            const float4* ls = (const float4*)xh_sh[wv];
#pragma unroll
            for (int k4 = 0; k4 < 16; ++k4) {
                float4 v = ls[k4];
                v0 = fmaf(v.x, W2[(4 * k4 + 0) * 16 + j], v0);
                v1 = fmaf(v.y, W2[(4 * k4 + 1) * 16 + j], v1);
                v2 = fmaf(v.z, W2[(4 * k4 + 2) * 16 + j], v2);
                v3 = fmaf(v.w, W2[(4 * k4 + 3) * 16 + j], v3);
            }
            h_sh[wv][32 + j] = fmaxf((v0 + v1) + (v2 + v3), 0.f);
        }
        __builtin_amdgcn_wave_barrier();

        if (j < 2) {
            float o = b3[j];
#pragma unroll
            for (int k = 0; k < 16; ++k)
                o = fmaf(h_sh[wv][32 + k], W3[k * 2 + j], o);
            out[b * 2 + j] = o;
        }
    }
}

// ===================== fallback: unchanged R4 fused kernel =====================
__global__ __launch_bounds__(64, 2)
void bilstm_fused_r4(const float* __restrict__ x,
                     const float* __restrict__ W0, const float* __restrict__ b0,
                     const float* __restrict__ Wf, const float* __restrict__ bf,
                     const float* __restrict__ Wb, const float* __restrict__ bb,
                     const float* __restrict__ W1, const float* __restrict__ b1,
                     const float* __restrict__ W2, const float* __restrict__ b2,
                     const float* __restrict__ W3, const float* __restrict__ b3,
                     float* __restrict__ out)
{
    __shared__ __align__(16) float lds_xh[16 * LDW];
    __shared__ __align__(16) float lds_g [16 * LDW];
    __shared__ __align__(16) float h_sh[48];

    const int j    = threadIdx.x;
    const int b    = blockIdx.x;
    const int nl   = j & 15;
    const int quad = j >> 4;

    int rot1 = __builtin_amdgcn_mov_dpp(j, 0x121, 0xf, 0xf, false);
    const bool plus = ((rot1 & 15) == ((nl + 1) & 15));

    float wfhp[16];
#pragma unroll
    for (int s = 0; s < 16; ++s) {
        const int srcq = plus ? ((nl + s) & 15) : ((nl + 16 - s) & 15);
        wfhp[s] = Wf[(64 + srcq) * 64 + j];
    }

    F8 B1h[4], B1l[4];
#pragma unroll
    for (int T = 0; T < 4; ++T) {
        float w[8];
#pragma unroll
        for (int e = 0; e < 8; ++e) {
            int k = quad * 8 + e;
            w[e] = (k < 20) ? W0[k * 64 + T * 16 + nl] : 0.f;
        }
        split_pack(w, B1h[T].u, B1l[T].u);
    }
    F8 B2h[4][2], B2l[4][2];
#pragma unroll
    for (int T = 0; T < 4; ++T)
#pragma unroll
        for (int KH = 0; KH < 2; ++KH) {
            float w[8];
#pragma unroll
            for (int e = 0; e < 8; ++e) {
                int k = KH * 32 + quad * 8 + e;
                w[e] = Wf[k * 64 + T * 16 + nl];
            }
            split_pack(w, B2h[T][KH].u, B2l[T][KH].u);
        }

    float b0v[4], bfv[4];
#pragma unroll
    for (int T = 0; T < 4; ++T) {
        b0v[T] = b0[T * 16 + nl];
        bfv[T] = bf[T * 16 + nl];
    }

    const float gmul  = (quad == 1) ? -2.f : -1.f;
    const float gbias = (quad == 2) ? 1.f : 0.f;
    const float amul  = (quad == 1) ? 2.f : 1.f;
    const float aadd  = (quad == 1) ? -1.f : 0.f;
    const bool  b0sel = (quad & 1) != 0;
    const bool  b1sel = (quad & 2) != 0;

    float c = 0.f, hh = 0.f;
    const float* xb = x + (size_t)b * (256 * 20);

#pragma unroll 1
    for (int ch = 0; ch < 16; ++ch) {
        const int t0 = ch * 16;
        const float* xrow = xb + (size_t)(t0 + nl) * 20;
        float xk[8];
#pragma unroll
        for (int e = 0; e < 8; ++e) {
            int k = quad * 8 + e;
            xk[e] = (k < 20) ? xrow[k] : 0.f;
        }
        F8 A1h, A1l;
        split_pack(xk, A1h.u, A1l.u);

        floatx4 acc1[4];
#pragma unroll
        for (int T = 0; T < 4; ++T) acc1[T] = (floatx4){b0v[T], b0v[T], b0v[T], b0v[T]};
#pragma unroll
        for (int T = 0; T < 4; ++T) {
            acc1[T] = __builtin_amdgcn_mfma_f32_16x16x32_bf16(A1h.v, B1h[T].v, acc1[T], 0, 0, 0);
            acc1[T] = __builtin_amdgcn_mfma_f32_16x16x32_bf16(A1l.v, B1h[T].v, acc1[T], 0, 0, 0);
            acc1[T] = __builtin_amdgcn_mfma_f32_16x16x32_bf16(A1h.v, B1l[T].v, acc1[T], 0, 0, 0);
        }
#pragma unroll
        for (int T = 0; T < 4; ++T)
#pragma unroll
            for (int reg = 0; reg < 4; ++reg)
                lds_xh[(quad * 4 + reg) * LDW + T * 16 + nl] = fmaxf(acc1[T][reg], 0.f);
        __builtin_amdgcn_wave_barrier();

        F8 A2h[2], A2l[2];
#pragma unroll
        for (int KH = 0; KH < 2; ++KH) {
            float xe[8];
#pragma unroll
            for (int e = 0; e < 8; ++e)
                xe[e] = lds_xh[nl * LDW + KH * 32 + quad * 8 + e];
            split_pack(xe, A2h[KH].u, A2l[KH].u);
        }

        floatx4 acc2[4];
#pragma unroll
        for (int T = 0; T < 4; ++T) acc2[T] = (floatx4){bfv[T], bfv[T], bfv[T], bfv[T]};
#pragma unroll
        for (int T = 0; T < 4; ++T)
#pragma unroll
            for (int KH = 0; KH < 2; ++KH) {
                acc2[T] = __builtin_amdgcn_mfma_f32_16x16x32_bf16(A2h[KH].v, B2h[T][KH].v, acc2[T], 0, 0, 0);
                acc2[T] = __builtin_amdgcn_mfma_f32_16x16x32_bf16(A2l[KH].v, B2h[T][KH].v, acc2[T], 0, 0, 0);
                acc2[T] = __builtin_amdgcn_mfma_f32_16x16x32_bf16(A2h[KH].v, B2l[T][KH].v, acc2[T], 0, 0, 0);
            }
#pragma unroll
        for (int T = 0; T < 4; ++T)
#pragma unroll
            for (int reg = 0; reg < 4; ++reg)
                lds_g[(quad * 4 + reg) * LDW + T * 16 + nl] = acc2[T][reg];
        __builtin_amdgcn_wave_barrier();

        float gcur = lds_g[j];
#pragma unroll
        for (int tau = 0; tau < 16; ++tau) {
            float gnext = lds_g[((tau < 15) ? (tau + 1) : 15) * LDW + j];
            float v0 = hh * wfhp[0];
            float v1 = ROT(hh, 1) * wfhp[1];
            float v2 = ROT(hh, 2) * wfhp[2];
            float v3 = ROT(hh, 3) * wfhp[3];
            v0 = fmaf(ROT(hh, 4),  wfhp[4],  v0);
            v1 = fmaf(ROT(hh, 5),  wfhp[5],  v1);
            v2 = fmaf(ROT(hh, 6),  wfhp[6],  v2);
            v3 = fmaf(ROT(hh, 7),  wfhp[7],  v3);
            v0 = fmaf(ROT(hh, 8),  wfhp[8],  v0);
            v1 = fmaf(ROT(hh, 9),  wfhp[9],  v1);
            v2 = fmaf(ROT(hh, 10), wfhp[10], v2);
            v3 = fmaf(ROT(hh, 11), wfhp[11], v3);
            v0 = fmaf(ROT(hh, 12), wfhp[12], v0);
            v1 = fmaf(ROT(hh, 13), wfhp[13], v1);
            v2 = fmaf(ROT(hh, 14), wfhp[14], v2);
            v3 = fmaf(ROT(hh, 15), wfhp[15], v3);
            float gated = gcur + ((v0 + v1) + (v2 + v3));

            float e = __expf(gmul * (gated + gbias));
            float y = __fdividef(1.f, 1.f + e);
            float a = fmaf(y, amul, aadd);

            float d1 = __shfl_xor(a, 16);
            float d2 = __shfl_xor(a, 32);
            float d3 = __shfl_xor(a, 48);
            float lo  = b0sel ? d1 : a;
            float hi  = b0sel ? d3 : d2;
            float lo1 = b0sel ? a  : d1;
            float hi1 = b0sel ? d2 : d3;
            float ai = b1sel ? hi  : lo;
            float ag = b1sel ? hi1 : lo1;
            float af = b1sel ? lo  : hi;
            float ao = b1sel ? lo1 : hi1;

            c  = fmaf(af, c, ai * ag);
            hh = ao * tanh_fast(c);
            gcur = gnext;
        }
    }

    if (j < 16) h_sh[j] = hh;
    __builtin_amdgcn_wave_barrier();

    {
        float u0 = bb[j], u1 = 0.f, u2 = 0.f, u3 = 0.f;
        const float* xr = &lds_xh[15 * LDW];
#pragma unroll
        for (int k4 = 0; k4 < 16; ++k4) {
            u0 = fmaf(xr[4 * k4 + 0], Wb[(4 * k4 + 0) * 64 + j], u0);
            u1 = fmaf(xr[4 * k4 + 1], Wb[(4 * k4 + 1) * 64 + j], u1);
            u2 = fmaf(xr[4 * k4 + 2], Wb[(4 * k4 + 2) * 64 + j], u2);
            u3 = fmaf(xr[4 * k4 + 3], Wb[(4 * k4 + 3) * 64 + j], u3);
        }
        float gated = (u0 + u1) + (u2 + u3);
        float e = __expf(gmul * gated);
        float y = __fdividef(1.f, 1.f + e);
        float a = fmaf(y, amul, aadd);
        float ai = __shfl(a, nl, 64);
        float ag = __shfl(a, nl + 16, 64);
        float ao = __shfl(a, nl + 48, 64);
        float cb = ai * ag;
        float hb = ao * tanh_fast(cb);
        __builtin_amdgcn_wave_barrier();
        if (j < 16) h_sh[16 + j] = hb;
        __builtin_amdgcn_wave_barrier();
    }

    {
        float u0 = b1[j], u1 = 0.f, u2 = 0.f, u3 = 0.f;
        const float4* hs = (const float4*)h_sh;
#pragma unroll
        for (int k4 = 0; k4 < 8; ++k4) {
            float4 v = hs[k4];
            u0 = fmaf(v.x, W1[(4 * k4 + 0) * 64 + j], u0);
            u1 = fmaf(v.y, W1[(4 * k4 + 1) * 64 + j], u1);
            u2 = fmaf(v.z, W1[(4 * k4 + 2) * 64 + j], u2);
            u3 = fmaf(v.w, W1[(4 * k4 + 3) * 64 + j], u3);
        }
        float l1 = fmaxf((u0 + u1) + (u2 + u3), 0.f);
        __builtin_amdgcn_wave_barrier();
        lds_g[j] = l1;
        __builtin_amdgcn_wave_barrier();

        if (j < 16) {
            float v0 = b2[j], v1 = 0.f, v2 = 0.f, v3 = 0.f;
            const float4* ls = (const float4*)lds_g;
#pragma unroll
            for (int k4 = 0; k4 < 16; ++k4) {
                float4 v = ls[k4];
                v0 = fmaf(v.x, W2[(4 * k4 + 0) * 16 + j], v0);
                v1 = fmaf(v.y, W2[(4 * k4 + 1) * 16 + j], v1);
                v2 = fmaf(v.z, W2[(4 * k4 + 2) * 16 + j], v2);
                v3 = fmaf(v.w, W2[(4 * k4 + 3) * 16 + j], v3);
            }
            h_sh[32 + j] = fmaxf((v0 + v1) + (v2 + v3), 0.f);
        }
        __builtin_amdgcn_wave_barrier();

        if (j < 2) {
            float o = b3[j];
#pragma unroll
            for (int k = 0; k < 16; ++k)
                o = fmaf(h_sh[32 + k], W3[k * 2 + j], o);
            out[b * 2 + j] = o;
        }
    }
}

extern "C" void kernel_launch(void* const* d_in, const int* in_sizes, int n_in,
                              void* d_out, int out_size, void* d_ws, size_t ws_size,
                              hipStream_t stream) {
    const float* x  = (const float*)d_in[0];
    const float* W0 = (const float*)d_in[1];
    const float* b0 = (const float*)d_in[2];
    const float* Wf = (const float*)d_in[3];
    const float* bf = (const float*)d_in[4];
    const float* Wb = (const float*)d_in[5];
    const float* bb = (const float*)d_in[6];
    const float* W1 = (const float*)d_in[7];
    const float* b1 = (const float*)d_in[8];
    const float* W2 = (const float*)d_in[9];
    const float* b2 = (const float*)d_in[10];
    const float* W3 = (const float*)d_in[11];
    const float* b3 = (const float*)d_in[12];
    float* outp = (float*)d_out;

    const size_t need = (size_t)4096 * 256 * 64 * sizeof(float);  // 268 MB
    if (ws_size >= need) {
        float* gpre = (float*)d_ws;
        hipLaunchKernelGGL(gpre_gemm, dim3(16384), dim3(256), 0, stream,
                           x, W0, b0, Wf, bf, gpre);
        hipLaunchKernelGGL(lstm_scan, dim3(1024), dim3(256), 0, stream,
                           gpre, x, W0, b0, Wf, Wb, bb, W1, b1, W2, b2, W3, b3, outp);
    } else {
        hipLaunchKernelGGL(bilstm_fused_r4, dim3(4096), dim3(64), 0, stream,
                           x, W0, b0, Wf, bf, Wb, bb, W1, b1, W2, b2, W3, b3, outp);
    }
}